// Round 6
// baseline (29.887 us; speedup 1.0000x reference)
//
#include <hip/hip_runtime.h>
#include <math.h>
#include <stdint.h>

// Problem constants (from reference): B=32, A=3, S=52, C=80
constexpr int NCELL = 32 * 3 * 52 * 52;   // 259584 = 64 * 4056
constexpr int PS = 85;                    // prediction channels (5 + C)
constexpr int NC = 80;                    // classes

constexpr int CPB = 64;                   // cells per block
constexpr int TPB = 256;                  // 4 lanes per cell
constexpr int NBLK = NCELL / CPB;         // 4056
constexpr int PRED_DW = CPB * PS;         // 5440 dwords (21760 B, 16B-aligned per block)
constexpr int PRED_V4 = PRED_DW / 4;      // 1360 float4
constexpr int PRED_FULL_IT = PRED_V4 / TPB;            // 5
constexpr int PRED_TAIL = PRED_V4 - PRED_FULL_IT * TPB; // 80
constexpr int TGT_DW = CPB * 6;           // 384 dwords
constexpr int TGT_V4 = TGT_DW / 4;        // 96 float4

// d_ws layout: per-block partials, 8 floats (32 B) per block.
// [b*8 + 0..5] = {bce_noobj, n_noobj, obj_term, n_obj, box_se, nll}

typedef __attribute__((address_space(3))) uint32_t       lds_u32_t;
typedef __attribute__((address_space(1))) const uint32_t glb_u32_t;

__global__ __launch_bounds__(TPB, 6) void yolo_main(const float* __restrict__ pred,
                                                    const float* __restrict__ tgt,
                                                    float* __restrict__ part)
{
    __shared__ float sp[PRED_DW];   // 21760 B
    __shared__ float st[TGT_DW];    // 1536 B
    __shared__ float red[4][6];

    int tid = threadIdx.x;

    // ---- stage: async global->LDS DMA for the 5 full float4 iterations ----
    // LDS dest is wave-linear (lane l of wave w at iteration it lands at
    // ((it*256 + w*64)*16 + l*16) -> exactly the HW's base + lane*size rule.
    const uint32_t* gpu = (const uint32_t*)(pred + (size_t)blockIdx.x * PRED_DW);
    #pragma unroll
    for (int it = 0; it < PRED_FULL_IT; ++it) {
        int idx4 = it * TPB + tid;    // float4 index
        __builtin_amdgcn_global_load_lds((glb_u32_t*)(gpu + idx4 * 4),
                                         (lds_u32_t*)(&sp[idx4 * 4]),
                                         16, 0, 0);
    }
    // tail (80 float4) + targets (96 float4): plain vector copies
    const float4* gp = (const float4*)(pred + (size_t)blockIdx.x * PRED_DW);
    const float4* gt = (const float4*)(tgt  + (size_t)blockIdx.x * TGT_DW);
    float4* sp4 = (float4*)sp;
    float4* st4 = (float4*)st;
    if (tid < PRED_TAIL)
        sp4[PRED_FULL_IT * TPB + tid] = gp[PRED_FULL_IT * TPB + tid];
    if (tid < TGT_V4)
        st4[tid] = gt[tid];

    __syncthreads();   // drains vmcnt + lgkmcnt, then barrier

    // ---- compute: 4 lanes per cell ----
    int c = tid >> 2;       // local cell 0..63
    int g = tid & 3;        // lane within group

    const float* row = sp + c * PS;

    // Each lane loads 20 interleaved logits: class = g + 4*j.
    float x[20];
    #pragma unroll
    for (int j = 0; j < 20; ++j) x[j] = row[5 + g + 4 * j];

    // group max: in-register tree, then 4-lane butterfly
    float m01 = fmaxf(x[0], x[1]),  m23 = fmaxf(x[2], x[3]);
    float m45 = fmaxf(x[4], x[5]),  m67 = fmaxf(x[6], x[7]);
    float m89 = fmaxf(x[8], x[9]),  mab = fmaxf(x[10], x[11]);
    float mcd = fmaxf(x[12], x[13]), mef = fmaxf(x[14], x[15]);
    float mgh = fmaxf(x[16], x[17]), mij = fmaxf(x[18], x[19]);
    float ma = fmaxf(fmaxf(m01, m23), fmaxf(m45, m67));
    float mb = fmaxf(fmaxf(m89, mab), fmaxf(mcd, mef));
    float m  = fmaxf(fmaxf(ma, mb), fmaxf(mgh, mij));
    m = fmaxf(m, __shfl_xor(m, 1));
    m = fmaxf(m, __shfl_xor(m, 2));

    int lbl = (int)st[c * 6 + 5];

    // exp-sum (2 accumulators) + label-logit select (compile-time reg idx)
    float seA = 0.f, seB = 0.f, sel = 0.f;
    #pragma unroll
    for (int j = 0; j < 20; j += 2) {
        seA += __expf(x[j]     - m);
        seB += __expf(x[j + 1] - m);
        if (g + 4 * j     == lbl) sel = x[j];
    }
    #pragma unroll
    for (int j = 1; j < 20; j += 2)
        if (g + 4 * j == lbl) sel = x[j];
    float se = seA + seB;
    se  += __shfl_xor(se, 1);
    se  += __shfl_xor(se, 2);
    sel += __shfl_xor(sel, 1);
    sel += __shfl_xor(sel, 2);

    float s0 = 0.f, s1 = 0.f, s2 = 0.f, s3 = 0.f, s4 = 0.f, s5 = 0.f;
    if (g == 0) {
        const float* t = st + c * 6;
        float t0 = t[0], t1 = t[1], t2 = t[2], t3 = t[3], t4 = t[4];
        float p0 = row[0], p1 = row[1], p2 = row[2], p3 = row[3], p4 = row[4];

        bool obj   = (t0 == 1.0f);
        bool noobj = (t0 == 0.0f);

        // BCE-with-logits on objectness
        float bce = fmaxf(p0, 0.0f) - p0 * t0 + log1pf(__expf(-fabsf(p0)));

        // midpoint IoU: b1 = pred[0:4], b2 = target[1:5]
        float b1x1 = p0 - p2 * 0.5f, b1y1 = p1 - p3 * 0.5f;
        float b1x2 = p0 + p2 * 0.5f, b1y2 = p1 + p3 * 0.5f;
        float b2x1 = t1 - t3 * 0.5f, b2y1 = t2 - t4 * 0.5f;
        float b2x2 = t1 + t3 * 0.5f, b2y2 = t2 + t4 * 0.5f;
        float xi1 = fmaxf(b1x1, b2x1), yi1 = fmaxf(b1y1, b2y1);
        float xi2 = fminf(b1x2, b2x2), yi2 = fminf(b1y2, b2y2);
        float inter = fmaxf(xi2 - xi1, 0.0f) * fmaxf(yi2 - yi1, 0.0f);
        float a1 = fabsf((b1x2 - b1x1) * (b1y2 - b1y1));
        float a2 = fabsf((b2x2 - b2x1) * (b2y2 - b2y1));
        float iou = inter / (a1 + a2 - inter + 1e-6f);

        // object loss term
        float pobj = 1.0f / (1.0f + __expf(-p0));
        float dob  = pobj - iou * t0;
        float objterm = dob * dob;

        // box loss term (sigmoid on pred[1:5])
        float d1 = 1.0f / (1.0f + __expf(-p1)) - t1;
        float d2 = 1.0f / (1.0f + __expf(-p2)) - t2;
        float d3 = 1.0f / (1.0f + __expf(-p3)) - t3;
        float d4 = 1.0f / (1.0f + __expf(-p4)) - t4;
        float boxse = d1*d1 + d2*d2 + d3*d3 + d4*d4;

        // class NLL
        float nll = __logf(se) - (sel - m);

        if (noobj) { s0 = bce; s1 = 1.0f; }
        if (obj)   { s2 = objterm; s3 = 1.0f; s4 = boxse; s5 = nll; }
    }

    // ---- wave reduction: data lives only on lanes ≡ 0 (mod 4) ----
    #pragma unroll
    for (int off = 4; off <= 32; off <<= 1) {
        s0 += __shfl_down(s0, off);
        s1 += __shfl_down(s1, off);
        s2 += __shfl_down(s2, off);
        s3 += __shfl_down(s3, off);
        s4 += __shfl_down(s4, off);
        s5 += __shfl_down(s5, off);
    }

    // ---- cross-wave reduction (4 waves), then TWO float4 stores per block ----
    int lane = tid & 63;
    int wid  = tid >> 6;
    if (lane == 0) {
        red[wid][0] = s0; red[wid][1] = s1; red[wid][2] = s2;
        red[wid][3] = s3; red[wid][4] = s4; red[wid][5] = s5;
    }
    __syncthreads();
    if (tid == 0) {
        float a0 = 0.f, a1 = 0.f, a2 = 0.f, a3 = 0.f, a4 = 0.f, a5 = 0.f;
        #pragma unroll
        for (int w = 0; w < 4; ++w) {
            a0 += red[w][0]; a1 += red[w][1]; a2 += red[w][2];
            a3 += red[w][3]; a4 += red[w][4]; a5 += red[w][5];
        }
        float4* slot = (float4*)(part + (size_t)blockIdx.x * 8);
        slot[0] = make_float4(a0, a1, a2, a3);
        slot[1] = make_float4(a4, a5, 0.0f, 0.0f);
    }
}

// Single-block reduction over the 4056 partial sets + final loss computation.
__global__ __launch_bounds__(1024) void yolo_reduce(const float* __restrict__ part,
                                                    float* __restrict__ out)
{
    float a0 = 0.f, a1 = 0.f, a2 = 0.f, a3 = 0.f, a4 = 0.f, a5 = 0.f;
    for (int i = threadIdx.x; i < NBLK; i += 1024) {
        const float4* slot = (const float4*)(part + (size_t)i * 8);
        float4 v0 = slot[0];
        float4 v1 = slot[1];
        a0 += v0.x; a1 += v0.y; a2 += v0.z;
        a3 += v0.w; a4 += v1.x; a5 += v1.y;
    }

    #pragma unroll
    for (int off = 32; off > 0; off >>= 1) {
        a0 += __shfl_down(a0, off);
        a1 += __shfl_down(a1, off);
        a2 += __shfl_down(a2, off);
        a3 += __shfl_down(a3, off);
        a4 += __shfl_down(a4, off);
        a5 += __shfl_down(a5, off);
    }

    __shared__ float red[16][6];
    int lane = threadIdx.x & 63;
    int wid  = threadIdx.x >> 6;
    if (lane == 0) {
        red[wid][0] = a0; red[wid][1] = a1; red[wid][2] = a2;
        red[wid][3] = a3; red[wid][4] = a4; red[wid][5] = a5;
    }
    __syncthreads();
    if (threadIdx.x == 0) {
        float b0 = 0.f, b1 = 0.f, b2 = 0.f, b3 = 0.f, b4 = 0.f, b5 = 0.f;
        #pragma unroll
        for (int w = 0; w < 16; ++w) {
            b0 += red[w][0]; b1 += red[w][1]; b2 += red[w][2];
            b3 += red[w][3]; b4 += red[w][4]; b5 += red[w][5];
        }
        float n_noobj = b1;
        float n_obj   = b3;
        // return order: (5*box, 1*object, 0.5*noobj, 1*class)
        out[0] = 5.0f * b4 / fmaxf(n_obj * 4.0f, 1.0f);
        out[1] = 1.0f * b2 / fmaxf(n_obj, 1.0f);
        out[2] = 0.5f * b0 / fmaxf(n_noobj, 1.0f);
        out[3] = 1.0f * b5 / fmaxf(n_obj, 1.0f);
    }
}

extern "C" void kernel_launch(void* const* d_in, const int* in_sizes, int n_in,
                              void* d_out, int out_size, void* d_ws, size_t ws_size,
                              hipStream_t stream)
{
    const float* pred = (const float*)d_in[0];
    const float* tgt  = (const float*)d_in[1];
    float* out  = (float*)d_out;
    float* part = (float*)d_ws;   // needs 4056*8*4 = 129,792 B

    yolo_main<<<NBLK, TPB, 0, stream>>>(pred, tgt, part);
    yolo_reduce<<<1, 1024, 0, stream>>>(part, out);
}

// Round 7
// 28.803 us; speedup vs baseline: 1.0376x; 1.0376x over previous
//
#include <hip/hip_runtime.h>
#include <math.h>
#include <stdint.h>

// Problem constants (from reference): B=32, A=3, S=52, C=80
constexpr int NCELL = 32 * 3 * 52 * 52;   // 259584 = 64 * 4056
constexpr int PS = 85;                    // prediction channels (5 + C)
constexpr int NC = 80;                    // classes

constexpr int CPB = 64;                   // cells per chunk
constexpr int TPB = 256;                  // 4 lanes per cell
constexpr int NCHUNK = NCELL / CPB;       // 4056
constexpr int GRID = 768;                 // 3 blocks/CU * 256 CU (persistent)
constexpr int PRED_DW = CPB * PS;         // 5440 dwords (21760 B)
constexpr int PRED_V4 = PRED_DW / 4;      // 1360 float4
constexpr int PRED_FULL_IT = PRED_V4 / TPB;            // 5
constexpr int PRED_TAIL = PRED_V4 - PRED_FULL_IT * TPB; // 80
constexpr int TGT_DW = CPB * 6;           // 384 dwords
constexpr int TGT_V4 = TGT_DW / 4;        // 96 float4

// d_ws: per-block partials, 8 floats (32 B) per block; GRID slots.
// [b*8 + 0..5] = {bce_noobj, n_noobj, obj_term, n_obj, box_se, nll}

typedef __attribute__((address_space(3))) uint32_t       lds_u32_t;
typedef __attribute__((address_space(1))) const uint32_t glb_u32_t;

__global__ __launch_bounds__(TPB, 3) void yolo_main(const float* __restrict__ pred,
                                                    const float* __restrict__ tgt,
                                                    float* __restrict__ part)
{
    __shared__ float sp[2][PRED_DW];   // 2 x 21760 B
    __shared__ float st[2][TGT_DW];    // 2 x 1536 B
    __shared__ float red[4][6];

    const int tid = threadIdx.x;
    const int c = tid >> 2;       // local cell 0..63
    const int g = tid & 3;        // lane within 4-lane group

    // persistent accumulators across chunks
    float s0 = 0.f, s1 = 0.f, s2 = 0.f, s3 = 0.f, s4 = 0.f, s5 = 0.f;

    // ---- DMA stage of one chunk into buffer `b` (fire-and-forget) ----
    auto STAGE = [&](int b, int chunk) {
        const uint32_t* gpu = (const uint32_t*)(pred + (size_t)chunk * PRED_DW);
        #pragma unroll
        for (int it = 0; it < PRED_FULL_IT; ++it) {
            int idx4 = it * TPB + tid;
            __builtin_amdgcn_global_load_lds((glb_u32_t*)(gpu + idx4 * 4),
                                             (lds_u32_t*)(&sp[b][idx4 * 4]),
                                             16, 0, 0);
        }
        if (tid < PRED_TAIL) {
            int idx4 = PRED_FULL_IT * TPB + tid;
            __builtin_amdgcn_global_load_lds((glb_u32_t*)(gpu + idx4 * 4),
                                             (lds_u32_t*)(&sp[b][idx4 * 4]),
                                             16, 0, 0);
        }
        const uint32_t* gtu = (const uint32_t*)(tgt + (size_t)chunk * TGT_DW);
        if (tid < TGT_V4) {
            __builtin_amdgcn_global_load_lds((glb_u32_t*)(gtu + tid * 4),
                                             (lds_u32_t*)(&st[b][tid * 4]),
                                             16, 0, 0);
        }
    };

    int chunk = blockIdx.x;
    STAGE(0, chunk);
    __syncthreads();            // cold drain (unavoidable once)

    int buf = 0;
    while (true) {
        int next = chunk + GRID;
        if (next < NCHUNK) STAGE(buf ^ 1, next);   // prefetch overlaps compute

        // ---- compute this chunk from LDS ----
        const float* row = sp[buf] + c * PS;
        const float* t   = st[buf] + c * 6;

        // 20 interleaved logits: class = g + 4*j
        float x[20];
        #pragma unroll
        for (int j = 0; j < 20; ++j) x[j] = row[5 + g + 4 * j];

        // group max: register tree + 4-lane butterfly
        float m01 = fmaxf(x[0], x[1]),  m23 = fmaxf(x[2], x[3]);
        float m45 = fmaxf(x[4], x[5]),  m67 = fmaxf(x[6], x[7]);
        float m89 = fmaxf(x[8], x[9]),  mab = fmaxf(x[10], x[11]);
        float mcd = fmaxf(x[12], x[13]), mef = fmaxf(x[14], x[15]);
        float mgh = fmaxf(x[16], x[17]), mij = fmaxf(x[18], x[19]);
        float ma = fmaxf(fmaxf(m01, m23), fmaxf(m45, m67));
        float mb = fmaxf(fmaxf(m89, mab), fmaxf(mcd, mef));
        float m  = fmaxf(fmaxf(ma, mb), fmaxf(mgh, mij));
        m = fmaxf(m, __shfl_xor(m, 1));
        m = fmaxf(m, __shfl_xor(m, 2));

        int lbl = (int)t[5];

        float seA = 0.f, seB = 0.f, sel = 0.f;
        #pragma unroll
        for (int j = 0; j < 20; j += 2) {
            seA += __expf(x[j]     - m);
            seB += __expf(x[j + 1] - m);
            if (g + 4 * j     == lbl) sel = x[j];
        }
        #pragma unroll
        for (int j = 1; j < 20; j += 2)
            if (g + 4 * j == lbl) sel = x[j];
        float se = seA + seB;
        se  += __shfl_xor(se, 1);
        se  += __shfl_xor(se, 2);
        sel += __shfl_xor(sel, 1);
        sel += __shfl_xor(sel, 2);

        if (g == 0) {
            float t0 = t[0], t1 = t[1], t2 = t[2], t3 = t[3], t4 = t[4];
            float p0 = row[0], p1 = row[1], p2 = row[2], p3 = row[3], p4 = row[4];

            bool obj   = (t0 == 1.0f);
            bool noobj = (t0 == 0.0f);

            // BCE-with-logits on objectness
            float bce = fmaxf(p0, 0.0f) - p0 * t0 + log1pf(__expf(-fabsf(p0)));

            // midpoint IoU: b1 = pred[0:4], b2 = target[1:5]
            float b1x1 = p0 - p2 * 0.5f, b1y1 = p1 - p3 * 0.5f;
            float b1x2 = p0 + p2 * 0.5f, b1y2 = p1 + p3 * 0.5f;
            float b2x1 = t1 - t3 * 0.5f, b2y1 = t2 - t4 * 0.5f;
            float b2x2 = t1 + t3 * 0.5f, b2y2 = t2 + t4 * 0.5f;
            float xi1 = fmaxf(b1x1, b2x1), yi1 = fmaxf(b1y1, b2y1);
            float xi2 = fminf(b1x2, b2x2), yi2 = fminf(b1y2, b2y2);
            float inter = fmaxf(xi2 - xi1, 0.0f) * fmaxf(yi2 - yi1, 0.0f);
            float a1 = fabsf((b1x2 - b1x1) * (b1y2 - b1y1));
            float a2 = fabsf((b2x2 - b2x1) * (b2y2 - b2y1));
            float iou = inter / (a1 + a2 - inter + 1e-6f);

            // object loss term
            float pobj = 1.0f / (1.0f + __expf(-p0));
            float dob  = pobj - iou * t0;

            // box loss term (sigmoid on pred[1:5])
            float d1 = 1.0f / (1.0f + __expf(-p1)) - t1;
            float d2 = 1.0f / (1.0f + __expf(-p2)) - t2;
            float d3 = 1.0f / (1.0f + __expf(-p3)) - t3;
            float d4 = 1.0f / (1.0f + __expf(-p4)) - t4;
            float boxse = d1*d1 + d2*d2 + d3*d3 + d4*d4;

            // class NLL
            float nll = __logf(se) - (sel - m);

            if (noobj) { s0 += bce; s1 += 1.0f; }
            if (obj)   { s2 += dob * dob; s3 += 1.0f; s4 += boxse; s5 += nll; }
        }

        if (next >= NCHUNK) break;
        __syncthreads();        // drains prefetch (latency hidden by compute) + buf-reuse barrier
        buf ^= 1;
        chunk = next;
    }

    // ---- wave reduction: data lives only on lanes ≡ 0 (mod 4) ----
    #pragma unroll
    for (int off = 4; off <= 32; off <<= 1) {
        s0 += __shfl_down(s0, off);
        s1 += __shfl_down(s1, off);
        s2 += __shfl_down(s2, off);
        s3 += __shfl_down(s3, off);
        s4 += __shfl_down(s4, off);
        s5 += __shfl_down(s5, off);
    }

    // ---- cross-wave reduction (4 waves), then two float4 stores per block ----
    int lane = tid & 63;
    int wid  = tid >> 6;
    if (lane == 0) {
        red[wid][0] = s0; red[wid][1] = s1; red[wid][2] = s2;
        red[wid][3] = s3; red[wid][4] = s4; red[wid][5] = s5;
    }
    __syncthreads();
    if (tid == 0) {
        float a0 = 0.f, a1 = 0.f, a2 = 0.f, a3 = 0.f, a4 = 0.f, a5 = 0.f;
        #pragma unroll
        for (int w = 0; w < 4; ++w) {
            a0 += red[w][0]; a1 += red[w][1]; a2 += red[w][2];
            a3 += red[w][3]; a4 += red[w][4]; a5 += red[w][5];
        }
        float4* slot = (float4*)(part + (size_t)blockIdx.x * 8);
        slot[0] = make_float4(a0, a1, a2, a3);
        slot[1] = make_float4(a4, a5, 0.0f, 0.0f);
    }
}

// Reduction over GRID partial sets + final loss computation.
__global__ __launch_bounds__(GRID) void yolo_reduce(const float* __restrict__ part,
                                                    float* __restrict__ out)
{
    // one slot per thread
    const float4* slot = (const float4*)(part + (size_t)threadIdx.x * 8);
    float4 v0 = slot[0];
    float4 v1 = slot[1];
    float a0 = v0.x, a1 = v0.y, a2 = v0.z, a3 = v0.w, a4 = v1.x, a5 = v1.y;

    #pragma unroll
    for (int off = 32; off > 0; off >>= 1) {
        a0 += __shfl_down(a0, off);
        a1 += __shfl_down(a1, off);
        a2 += __shfl_down(a2, off);
        a3 += __shfl_down(a3, off);
        a4 += __shfl_down(a4, off);
        a5 += __shfl_down(a5, off);
    }

    __shared__ float red[12][6];
    int lane = threadIdx.x & 63;
    int wid  = threadIdx.x >> 6;
    if (lane == 0) {
        red[wid][0] = a0; red[wid][1] = a1; red[wid][2] = a2;
        red[wid][3] = a3; red[wid][4] = a4; red[wid][5] = a5;
    }
    __syncthreads();
    if (threadIdx.x == 0) {
        float b0 = 0.f, b1 = 0.f, b2 = 0.f, b3 = 0.f, b4 = 0.f, b5 = 0.f;
        #pragma unroll
        for (int w = 0; w < 12; ++w) {
            b0 += red[w][0]; b1 += red[w][1]; b2 += red[w][2];
            b3 += red[w][3]; b4 += red[w][4]; b5 += red[w][5];
        }
        float n_noobj = b1;
        float n_obj   = b3;
        // return order: (5*box, 1*object, 0.5*noobj, 1*class)
        out[0] = 5.0f * b4 / fmaxf(n_obj * 4.0f, 1.0f);
        out[1] = 1.0f * b2 / fmaxf(n_obj, 1.0f);
        out[2] = 0.5f * b0 / fmaxf(n_noobj, 1.0f);
        out[3] = 1.0f * b5 / fmaxf(n_obj, 1.0f);
    }
}

extern "C" void kernel_launch(void* const* d_in, const int* in_sizes, int n_in,
                              void* d_out, int out_size, void* d_ws, size_t ws_size,
                              hipStream_t stream)
{
    const float* pred = (const float*)d_in[0];
    const float* tgt  = (const float*)d_in[1];
    float* out  = (float*)d_out;
    float* part = (float*)d_ws;   // needs GRID*8*4 = 24,576 B

    yolo_main<<<GRID, TPB, 0, stream>>>(pred, tgt, part);
    yolo_reduce<<<1, GRID, 0, stream>>>(part, out);
}